// Round 2
// baseline (68.996 us; speedup 1.0000x reference)
//
#include <hip/hip_runtime.h>
#include <math.h>
#include <type_traits>

#define QDEPTH 10
#define WIRES 10
#define NSTATE 1024
#define NGATES (QDEPTH * WIRES)

// ---------------------------------------------------------------------------
// Compile-time GF(2) linear-map machinery. The CNOT layers are bit-linear
// index permutations; we never move data, we just track the map.
// Map A: bit b of A(v) = parity(A.row[b] & v).
// ---------------------------------------------------------------------------
struct GF { unsigned short row[WIRES]; };

constexpr GF gf_identity() {
    GF g{};
    for (int b = 0; b < WIRES; ++b) g.row[b] = (unsigned short)(1u << b);
    return g;
}
constexpr GF gf_compose(const GF& A, const GF& B) {  // C(v) = A(B(v))
    GF c{};
    for (int b = 0; b < WIRES; ++b) {
        unsigned short r = 0;
        for (int k = 0; k < WIRES; ++k)
            if ((A.row[b] >> k) & 1) r ^= B.row[k];
        c.row[b] = r;
    }
    return c;
}
constexpr GF gf_sigma(int q, int r) {  // CNOT: ctrl wire q, tgt wire (q+r)%10
    GF g = gf_identity();
    int cb = (WIRES - 1) - q;
    int tb = (WIRES - 1) - ((q + r) % WIRES);
    g.row[tb] = (unsigned short)((1u << tb) | (1u << cb));
    return g;
}
constexpr int parity16(unsigned v) { v ^= v >> 8; v ^= v >> 4; v ^= v >> 2; v ^= v >> 1; return (int)(v & 1u); }

struct Tables {
    unsigned short mask[NGATES];   // stored-index XOR mask pairing gate g
    unsigned short prow[NGATES];   // parity row: logical bit = parity(prow & s)
    unsigned short outrow[WIRES];  // final logical index bits from stored s
};

constexpr Tables make_tables() {
    Tables t{};
    GF L = gf_identity(), Linv = gf_identity();
    for (int l = 0; l < QDEPTH; ++l) {
        for (int q = 0; q < WIRES; ++q) {
            int b = (WIRES - 1) - q;
            unsigned short m = 0;
            for (int bp = 0; bp < WIRES; ++bp)
                m |= (unsigned short)(((Linv.row[bp] >> b) & 1u) << bp);
            t.mask[l * WIRES + q] = m;          // m = Linv(e_b)
            t.prow[l * WIRES + q] = L.row[b];
        }
        int r = (l % (WIRES - 1)) + 1;
        // state_new[j] = state_old[P(j)], P = s0∘s1∘...∘s9 (s9 innermost)
        GF P = gf_sigma(WIRES - 1, r);
        for (int q = WIRES - 2; q >= 0; --q) P = gf_compose(gf_sigma(q, r), P);
        GF Pinv = gf_sigma(0, r);
        for (int q = 1; q < WIRES; ++q) Pinv = gf_compose(gf_sigma(q, r), Pinv);
        L = gf_compose(Pinv, L);      // L_new = P^{-1} ∘ L
        Linv = gf_compose(Linv, P);   // Linv_new = Linv ∘ P
    }
    for (int b = 0; b < WIRES; ++b) t.outrow[b] = L.row[b];
    return t;
}

constexpr Tables TAB = make_tables();

constexpr unsigned out_reg(int j) {  // register-bit part of output index
    unsigned o = 0;
    for (int b = 0; b < WIRES; ++b)
        o |= (unsigned)parity16((unsigned)(TAB.outrow[b] >> 6) & (unsigned)j) << b;
    return o;
}

// compile-time-index for loop
template <int N, int I = 0, typename F>
__device__ __forceinline__ void static_for(F&& f) {
    if constexpr (I < N) {
        f(std::integral_constant<int, I>{});
        static_for<N, I + 1>(f);
    }
}

// ---------------------------------------------------------------------------
// Kernel 1: 100 Rot gates. SU(2): g11 = conj(g00), g10 = -conj(g01), so we
// only store g00 and g01: (g00r, g00i, g01r, g01i) per gate.
// ---------------------------------------------------------------------------
__global__ void gates_kernel(const float* __restrict__ w, float* __restrict__ g) {
    int i = threadIdx.x;
    if (i >= NGATES) return;
    float phi = tanhf(w[3 * i + 0]);
    float th  = tanhf(w[3 * i + 1]);
    float om  = tanhf(w[3 * i + 2]);
    float c = cosf(0.5f * th), s = sinf(0.5f * th);
    float a = 0.5f * (phi + om), d = 0.5f * (phi - om);
    float* p = g + 4 * i;
    p[0] =  cosf(a) * c;   // g00r
    p[1] = -sinf(a) * c;   // g00i
    p[2] = -cosf(d) * s;   // g01r
    p[3] = -sinf(d) * s;   // g01i
}

// ---------------------------------------------------------------------------
// Kernel 2: one wave (64 threads) per batch element; entire state in VGPRs:
// stored index s = (reg j [4b] << 6) | lane [6b]. No barriers anywhere.
// ---------------------------------------------------------------------------
__global__ __launch_bounds__(64) void sim_kernel(const float* __restrict__ x,
                                                 const float* __restrict__ gates,
                                                 float* __restrict__ out) {
    __shared__ float obuf[NSTATE];
    const int b = blockIdx.x;
    const int lane = threadIdx.x;
    const float* xb = x + (size_t)b * NSTATE;

    float sr[16], si[16];

    // ---- amplitude embedding: load + L2 normalize (all in registers) ----
    float ss = 0.f;
    static_for<16>([&](auto J) {
        constexpr int j = J.value;
        float v = xb[(j << 6) + lane];
        sr[j] = v; si[j] = 0.f;
        ss = fmaf(v, v, ss);
    });
#pragma unroll
    for (int off = 1; off < 64; off <<= 1) ss += __shfl_xor(ss, off);
    const float nrm = 1.0f / sqrtf(ss);
    static_for<16>([&](auto J) { sr[J.value] *= nrm; });

    // ---- 100 Rot gates with lazily-tracked index map ----
    static_for<NGATES>([&](auto G) {
        constexpr int g = G.value;
        constexpr unsigned M = TAB.mask[g];
        constexpr unsigned A = TAB.prow[g];
        constexpr int ML = (int)(M & 63u);   // lane part of pair mask
        constexpr int MR = (int)(M >> 6);    // register part
        constexpr int AL = (int)(A & 63u);   // lane part of parity row
        constexpr int AR = (int)(A >> 6);

        const float4 gc = *reinterpret_cast<const float4*>(gates + 4 * g);
        // per-lane parity contribution
        const bool pl = (__popc(lane & AL) & 1) != 0;
        // element parity p selects (gA,gB) = p ? (g11,g10) : (g00,g01).
        // SU(2): only Ai and Br flip sign with p; Ar=gc.x, Bi=gc.w shared.
        const float Ai0 = pl ? -gc.y : gc.y;  // for elements with reg-parity 0
        const float Br0 = pl ? -gc.z : gc.z;
        const float Ai1 = -Ai0;               // reg-parity 1
        const float Br1 = -Br0;

        // n = (Ar + i·Ai)·self + (Br + i·Bi)·partner
        auto upd = [&](float s_r, float s_i, float p_r, float p_i,
                       float Ai, float Br, float& nr, float& ni) {
            nr = fmaf(gc.x, s_r, fmaf(-Ai, s_i, fmaf(Br, p_r, -gc.w * p_i)));
            ni = fmaf(gc.x, s_i, fmaf( Ai, s_r, fmaf(Br, p_i,  gc.w * p_r)));
        };

        static_for<16>([&](auto J) {
            constexpr int j = J.value;
            constexpr int jp = j ^ MR;
            constexpr int cj = parity16((unsigned)(AR & j));
            if constexpr (MR == 0) {
                // partner purely cross-lane; in-place safe (shfl reads old)
                float pr = __shfl_xor(sr[j], ML);
                float pi = __shfl_xor(si[j], ML);
                float nr, ni;
                upd(sr[j], si[j], pr, pi, cj ? Ai1 : Ai0, cj ? Br1 : Br0, nr, ni);
                sr[j] = nr; si[j] = ni;
            } else if constexpr (j < jp) {
                constexpr int cp = parity16((unsigned)(AR & jp));
                float pjr, pji, ppr, ppi;
                if constexpr (ML != 0) {
                    pjr = __shfl_xor(sr[jp], ML); pji = __shfl_xor(si[jp], ML);
                    ppr = __shfl_xor(sr[j],  ML); ppi = __shfl_xor(si[j],  ML);
                } else {
                    pjr = sr[jp]; pji = si[jp];
                    ppr = sr[j];  ppi = si[j];
                }
                float n1r, n1i, n2r, n2i;
                upd(sr[j],  si[j],  pjr, pji, cj ? Ai1 : Ai0, cj ? Br1 : Br0, n1r, n1i);
                upd(sr[jp], si[jp], ppr, ppi, cp ? Ai1 : Ai0, cp ? Br1 : Br0, n2r, n2i);
                sr[j]  = n1r; si[j]  = n1i;
                sr[jp] = n2r; si[jp] = n2i;
            }
        });
    });

    // ---- probs, reorder through LDS (single wave -> no barrier), store ----
    int ol = 0;
    static_for<WIRES>([&](auto B) {
        constexpr int b2 = B.value;
        constexpr int rl = (int)(TAB.outrow[b2] & 63u);
        ol |= (__popc(lane & rl) & 1) << b2;
    });
    static_for<16>([&](auto J) {
        constexpr int j = J.value;
        constexpr unsigned oj = out_reg(j);
        float p = fmaf(sr[j], sr[j], si[j] * si[j]) * (float)NSTATE;
        p = fminf(p, 1.0f);
        obuf[oj ^ (unsigned)ol] = p;
    });
    float* ob = out + (size_t)b * NSTATE;
    static_for<16>([&](auto J) {
        constexpr int j = J.value;
        ob[(j << 6) + lane] = obuf[(j << 6) + lane];
    });
}

extern "C" void kernel_launch(void* const* d_in, const int* in_sizes, int n_in,
                              void* d_out, int out_size, void* d_ws, size_t ws_size,
                              hipStream_t stream) {
    const float* x = (const float*)d_in[0];   // [1024,1,32,32] f32
    const float* w = (const float*)d_in[1];   // [10,10,3] f32
    float* out   = (float*)d_out;             // [1024,1,32,32] f32
    float* gates = (float*)d_ws;              // 100*4 floats scratch

    gates_kernel<<<1, 128, 0, stream>>>(w, gates);
    sim_kernel<<<1024, 64, 0, stream>>>(x, gates, out);
}

// Round 3
// 51.983 us; speedup vs baseline: 1.3273x; 1.3273x over previous
//
#include <hip/hip_runtime.h>
#include <math.h>
#include <type_traits>

#define QDEPTH 10
#define WIRES 10
#define NSTATE 1024
#define NGATES (QDEPTH * WIRES)

// ---------------------------------------------------------------------------
// Compile-time circuit structure.
// Logical amp index i: bit (9-q) = wire q. Stored index s = (reg j<<6)|lane.
// Epoch layouts: A: i = s ; B: i_b = s_{(b+4)%10} ; C: i_b = s_{(b+8)%10}.
// Epoch A holds wires 0-3 on reg bits, B wires 4-7, C wires 8-9.
// LDS word-swizzle W(s) = s ^ ((s>>5)&31) keeps bounces bank-conflict-free.
// ---------------------------------------------------------------------------
constexpr unsigned sigma_apply(int q, int r, unsigned i) {
    int cb = 9 - q, tb = 9 - ((q + r) % 10);
    return i ^ (((i >> cb) & 1u) << tb);
}
constexpr unsigned G_apply(int l, unsigned i) {
    int r = (l % 9) + 1;
    for (int q = 9; q >= 0; --q) i = sigma_apply(q, r, i);  // G = s0∘s1∘…∘s9
    return i;
}
constexpr unsigned swz(unsigned w) { return w ^ ((w >> 5) & 31u); }

struct PermT { unsigned short t[QDEPTH][NSTATE]; };
constexpr PermT make_perm() {
    PermT p{};
    for (int l = 0; l < QDEPTH; ++l)
        for (unsigned ns = 0; ns < NSTATE; ++ns) {
            unsigned g = G_apply(l, ns);                    // pre-CNOT logical index
            unsigned src = ((g >> 2) | (g << 8)) & 1023u;   // its slot in layout C
            p.t[l][ns] = (unsigned short)swz(src);          // swizzled LDS word idx
        }
    return p;
}
__constant__ PermT PERM = make_perm();

template <int N, int I = 0, typename F>
__device__ __forceinline__ void static_for(F&& f) {
    if constexpr (I < N) {
        f(std::integral_constant<int, I>{});
        static_for<N, I + 1>(f);
    }
}

// ---------------------------------------------------------------------------
// Kernel 1: 100 Rot gates; SU(2) so we store only (g00r,g00i,g01r,g01i).
// ---------------------------------------------------------------------------
__global__ void gates_kernel(const float* __restrict__ w, float* __restrict__ g) {
    int i = threadIdx.x;
    if (i >= NGATES) return;
    float phi = tanhf(w[3 * i + 0]);
    float th  = tanhf(w[3 * i + 1]);
    float om  = tanhf(w[3 * i + 2]);
    float c = cosf(0.5f * th), s = sinf(0.5f * th);
    float a = 0.5f * (phi + om), d = 0.5f * (phi - om);
    float* p = g + 4 * i;
    p[0] =  cosf(a) * c;   // g00r
    p[1] = -sinf(a) * c;   // g00i
    p[2] = -cosf(d) * s;   // g01r
    p[3] = -sinf(d) * s;   // g01i
}

// Gate on register bit JB: pairs (j, j|1<<JB), static signs, SGPR coeffs.
template <int JB>
__device__ __forceinline__ void apply_gate(float (&sr)[16], float (&si)[16],
                                           const float* __restrict__ gp) {
    const float Ar = gp[0], Ai = gp[1], Br = gp[2], Bi = gp[3];
    static_for<8>([&](auto P) {
        constexpr int p  = P.value;
        constexpr int lo = p & ((1 << JB) - 1);
        constexpr int j  = ((p & ~((1 << JB) - 1)) << 1) | lo;
        constexpr int jp = j | (1 << JB);
        float ar = sr[j], ai = si[j], br = sr[jp], bi = si[jp];
        // n_j  = g00*a + g01*b ; n_jp = -conj(g01)*a + conj(g00)*b
        sr[j]  = fmaf(Ar, ar, fmaf(-Ai, ai, fmaf(Br, br, -Bi * bi)));
        si[j]  = fmaf(Ar, ai, fmaf( Ai, ar, fmaf(Br, bi,  Bi * br)));
        sr[jp] = fmaf(-Br, ar, fmaf(-Bi, ai, fmaf(Ar, br,  Ai * bi)));
        si[jp] = fmaf(-Br, ai, fmaf( Bi, ar, fmaf(Ar, bi, -Ai * br)));
    });
}

// ---------------------------------------------------------------------------
// Kernel 2: 1 wave = 1 batch element; state in 32 VGPRs; compact layer loop.
// ---------------------------------------------------------------------------
__global__ __launch_bounds__(64) void sim_kernel(const float* __restrict__ x,
                                                 const float* __restrict__ gates,
                                                 float* __restrict__ out) {
    __shared__ float lds[2048];          // [0..1023]=re, [1024..2047]=im
    const int b = blockIdx.x;
    const int lane = threadIdx.x;
    const float* xb = x + (size_t)b * NSTATE;

    float sr[16], si[16];

    // ---- amplitude embedding + L2 normalize ----
    float ss = 0.f;
    static_for<16>([&](auto J) {
        constexpr int j = J.value;
        float v = xb[(j << 6) + lane];
        sr[j] = v; si[j] = 0.f;
        ss = fmaf(v, v, ss);
    });
#pragma unroll
    for (int off = 1; off < 64; off <<= 1) ss += __shfl_xor(ss, off);
    const float nrm = 1.0f / sqrtf(ss);
    static_for<16>([&](auto J) { sr[J.value] *= nrm; });

    // per-lane bounce address bases (swizzled word indices)
    const int wbase = lane ^ (lane >> 5);
    const int rbase = ((((lane & 15) << 6) | (lane >> 4)) ^ ((lane & 15) << 1));

    // rotate-by-4 LDS bounce: src = ((ns>>4)|(ns<<6))&1023, both sides swizzled
    auto bounce_rot = [&]() {
        static_for<16>([&](auto J) {
            constexpr int j = J.value;
            constexpr int CJ = ((j << 1) & 31) | (j << 6);
            int w = wbase ^ CJ;
            lds[w] = sr[j]; lds[w + 1024] = si[j];
        });
        static_for<16>([&](auto J) {
            constexpr int j = J.value;
            constexpr int RJ = (j << 2) ^ (j >> 3);
            int t = rbase ^ RJ;
            sr[j] = lds[t]; si[j] = lds[t + 1024];
        });
    };

#pragma unroll 1
    for (int l = 0; l < QDEPTH; ++l) {
        const float* gl = gates + 40 * l;

        // ---- epoch A: wires 0..3 on reg bits 3..0 ----
        static_for<4>([&](auto G_) {
            constexpr int g = G_.value;
            apply_gate<3 - g>(sr, si, gl + 4 * g);
        });
        bounce_rot();

        // ---- epoch B: wires 4..7 ----
        static_for<4>([&](auto G_) {
            constexpr int g = G_.value;
            apply_gate<3 - g>(sr, si, gl + 4 * (4 + g));
        });
        bounce_rot();

        // ---- epoch C: wires 8,9 then CNOT-perm bounce back to layout A ----
        const unsigned short* pt = PERM.t[l];
        unsigned ta[16];
        static_for<16>([&](auto J) {          // issue table loads early
            constexpr int j = J.value;
            ta[j] = pt[(j << 6) | lane];
        });
        static_for<2>([&](auto G_) {
            constexpr int g = G_.value;
            apply_gate<3 - g>(sr, si, gl + 4 * (8 + g));
        });
        static_for<16>([&](auto J) {
            constexpr int j = J.value;
            constexpr int CJ = ((j << 1) & 31) | (j << 6);
            int w = wbase ^ CJ;
            lds[w] = sr[j]; lds[w + 1024] = si[j];
        });
        static_for<16>([&](auto J) {
            constexpr int j = J.value;
            int t = (int)ta[j];
            sr[j] = lds[t]; si[j] = lds[t + 1024];
        });
    }

    // ---- probs = clip(|amp|^2 * 1024, 0, 1); layout is logical order ----
    float* ob = out + (size_t)b * NSTATE;
    static_for<16>([&](auto J) {
        constexpr int j = J.value;
        float p = fmaf(sr[j], sr[j], si[j] * si[j]) * (float)NSTATE;
        ob[(j << 6) + lane] = fminf(p, 1.0f);
    });
}

extern "C" void kernel_launch(void* const* d_in, const int* in_sizes, int n_in,
                              void* d_out, int out_size, void* d_ws, size_t ws_size,
                              hipStream_t stream) {
    const float* x = (const float*)d_in[0];   // [1024,1,32,32] f32
    const float* w = (const float*)d_in[1];   // [10,10,3] f32
    float* out   = (float*)d_out;             // [1024,1,32,32] f32
    float* gates = (float*)d_ws;              // 100*4 floats scratch

    gates_kernel<<<1, 128, 0, stream>>>(w, gates);
    sim_kernel<<<1024, 64, 0, stream>>>(x, gates, out);
}

// Round 4
// 46.461 us; speedup vs baseline: 1.4850x; 1.1188x over previous
//
#include <hip/hip_runtime.h>
#include <math.h>
#include <type_traits>

#define QDEPTH 10
#define WIRES 10
#define NSTATE 1024
#define NGATES (QDEPTH * WIRES)

// ---------------------------------------------------------------------------
// Compile-time circuit structure.
// Logical amp index i (bit 9-q = wire q) == stored index s = w<<9 | j<<6 | lane.
// Wire 0 -> wave bit (folded into gather); wires 1-3 -> reg bits 2..0;
// wires 4-9 -> lane bits 5..0 (shuffles).
// Per-layer CNOT chain: new[i] = old[G_l(i)], G_l = GF(2)-linear.
// LDS word swizzle swz(x) = x ^ ((x>>5)&31): write side provably <=2-way.
// ---------------------------------------------------------------------------
constexpr unsigned sigma_apply(int q, int r, unsigned i) {
    int cb = 9 - q, tb = 9 - ((q + r) % 10);
    return i ^ (((i >> cb) & 1u) << tb);
}
constexpr unsigned G_apply(int l, unsigned i) {
    int r = (l % 9) + 1;
    for (int q = 9; q >= 0; --q) i = sigma_apply(q, r, i);  // G = s0∘s1∘…∘s9
    return i;
}
constexpr unsigned swz(unsigned w) { return w ^ ((w >> 5) & 31u); }

struct PermT { unsigned short t[QDEPTH][NSTATE]; };
constexpr PermT make_perm() {
    PermT p{};
    for (int l = 0; l < QDEPTH; ++l)
        for (unsigned s = 0; s < NSTATE; ++s)
            p.t[l][s] = (unsigned short)swz(G_apply(l, s));  // bit9 preserved
    return p;
}
__constant__ PermT PERM = make_perm();

template <int N, int I = 0, typename F>
__device__ __forceinline__ void static_for(F&& f) {
    if constexpr (I < N) {
        f(std::integral_constant<int, I>{});
        static_for<N, I + 1>(f);
    }
}

// ---------------------------------------------------------------------------
// Kernel 1: 100 Rot gates; SU(2) so only (g00r,g00i,g01r,g01i) per gate.
// ---------------------------------------------------------------------------
__global__ void gates_kernel(const float* __restrict__ w, float* __restrict__ g) {
    int i = threadIdx.x;
    if (i >= NGATES) return;
    float phi = tanhf(w[3 * i + 0]);
    float th  = tanhf(w[3 * i + 1]);
    float om  = tanhf(w[3 * i + 2]);
    float c = cosf(0.5f * th), s = sinf(0.5f * th);
    float a = 0.5f * (phi + om), d = 0.5f * (phi - om);
    float* p = g + 4 * i;
    p[0] =  cosf(a) * c;   // g00r
    p[1] = -sinf(a) * c;   // g00i
    p[2] = -cosf(d) * s;   // g01r
    p[3] = -sinf(d) * s;   // g01i
}

// Gate on register bit JB of an 8-register state: 4 static pairs, pure FMA.
template <int JB>
__device__ __forceinline__ void apply_gate(float (&sr)[8], float (&si)[8],
                                           const float* __restrict__ gp) {
    const float Ar = gp[0], Ai = gp[1], Br = gp[2], Bi = gp[3];
    static_for<4>([&](auto P) {
        constexpr int p  = P.value;
        constexpr int lo = p & ((1 << JB) - 1);
        constexpr int j  = ((p & ~((1 << JB) - 1)) << 1) | lo;
        constexpr int jp = j | (1 << JB);
        float ar = sr[j], ai = si[j], br = sr[jp], bi = si[jp];
        sr[j]  = fmaf(Ar, ar, fmaf(-Ai, ai, fmaf(Br, br, -Bi * bi)));
        si[j]  = fmaf(Ar, ai, fmaf( Ai, ar, fmaf(Br, bi,  Bi * br)));
        sr[jp] = fmaf(-Br, ar, fmaf(-Bi, ai, fmaf(Ar, br,  Ai * bi)));
        si[jp] = fmaf(-Br, ai, fmaf( Bi, ar, fmaf(Ar, bi, -Ai * br)));
    });
}

// ---------------------------------------------------------------------------
// Kernel 2: 2 waves per batch element (128 thr); 8 complex amps per thread.
// One barrier + one LDS round-trip per layer (double-buffered).
// ---------------------------------------------------------------------------
__global__ __launch_bounds__(128) void sim_kernel(const float* __restrict__ x,
                                                  const float* __restrict__ gates,
                                                  float* __restrict__ out) {
    __shared__ float lds[2][2048];     // [buf][0..1023]=re, [1024..2047]=im
    __shared__ float wsum[2];
    const int b    = blockIdx.x;
    const int tid  = threadIdx.x;
    const int w    = tid >> 6;         // wave id (wire-0 bit)
    const int lane = tid & 63;
    const int whi  = w << 9;
    const float* xb = x + (size_t)b * NSTATE;

    float sr[8], si[8];

    // ---- amplitude embedding + cross-wave L2 normalize ----
    float ss = 0.f;
    static_for<8>([&](auto J) {
        constexpr int j = J.value;
        float v = xb[whi | (j << 6) | lane];
        sr[j] = v; si[j] = 0.f;
        ss = fmaf(v, v, ss);
    });
#pragma unroll
    for (int off = 1; off < 64; off <<= 1) ss += __shfl_xor(ss, off);
    if (lane == 0) wsum[w] = ss;
    __syncthreads();
    const float nrm = 1.0f / sqrtf(wsum[0] + wsum[1]);
    static_for<8>([&](auto J) { sr[J.value] *= nrm; });

#pragma unroll 1
    for (int l = 0; l < QDEPTH; ++l) {
        float* buf = lds[l & 1];
        const float* gl = gates + 40 * l;
        const unsigned short* pt = PERM.t[l];

        // prefetch gather addresses (hide L2 latency under gate compute)
        int ta[8];
        static_for<8>([&](auto J) {
            constexpr int j = J.value;
            ta[j] = (int)pt[whi | (j << 6) | lane];
        });

        // ---- wires 1..3 on reg bits 2..0 (pure FMA) ----
        apply_gate<2>(sr, si, gl + 4);
        apply_gate<1>(sr, si, gl + 8);
        apply_gate<0>(sr, si, gl + 12);

        // ---- wires 4..9 on lane bits 5..0 (shuffles, no barrier) ----
        static_for<6>([&](auto Q) {
            constexpr int qq = Q.value;              // wire 4+qq
            constexpr int m  = 1 << (5 - qq);
            const float* gp = gl + 4 * (4 + qq);
            const float Ar = gp[0], Ai = gp[1], Br = gp[2], Bi = gp[3];
            const bool hi = (lane & m) != 0;
            const float Ais = hi ? -Ai : Ai;         // row-1: conj/neg pattern
            const float Brs = hi ? -Br : Br;
            static_for<8>([&](auto J) {
                constexpr int j = J.value;
                float pr = __shfl_xor(sr[j], m);
                float pi = __shfl_xor(si[j], m);
                float nr = fmaf(Ar, sr[j], fmaf(-Ais, si[j], fmaf(Brs, pr, -Bi * pi)));
                float ni = fmaf(Ar, si[j], fmaf( Ais, sr[j], fmaf(Brs, pi,  Bi * pr)));
                sr[j] = nr; si[j] = ni;
            });
        });

        // ---- write state to LDS (swizzled; <=2-way by construction) ----
        static_for<8>([&](auto J) {
            constexpr int j = J.value;
            int s = whi | (j << 6) | lane;
            int a = s ^ ((s >> 5) & 31);
            buf[a] = sr[j]; buf[a + 1024] = si[j];
        });
        __syncthreads();

        // ---- wire 0 (bit 9) folded into CNOT gather ----
        // new[s] = CA*old[p] + CB*old[p^512], p = G_l(s), row = bit9(p).
        const float Ar = gl[0], Ai = gl[1], Br = gl[2], Bi = gl[3];
        static_for<8>([&](auto J) {
            constexpr int j = J.value;
            int a0 = ta[j];
            int a1 = a0 ^ 528;                       // swz(p^512) = swz(p)^528
            float vr = buf[a0], vi = buf[a0 + 1024];
            float pr = buf[a1], pi = buf[a1 + 1024];
            const bool hi2 = (a0 & 512) != 0;        // bit9 preserved by swz
            float Ais = hi2 ? -Ai : Ai;
            float Brs = hi2 ? -Br : Br;
            sr[j] = fmaf(Ar, vr, fmaf(-Ais, vi, fmaf(Brs, pr, -Bi * pi)));
            si[j] = fmaf(Ar, vi, fmaf( Ais, vr, fmaf(Brs, pi,  Bi * pr)));
        });
        // no trailing barrier: next layer writes the other buffer
    }

    // ---- probs = clip(|amp|^2 * 1024, 0, 1); layout already logical ----
    float* ob = out + (size_t)b * NSTATE;
    static_for<8>([&](auto J) {
        constexpr int j = J.value;
        float p = fmaf(sr[j], sr[j], si[j] * si[j]) * (float)NSTATE;
        ob[whi | (j << 6) | lane] = fminf(p, 1.0f);
    });
}

extern "C" void kernel_launch(void* const* d_in, const int* in_sizes, int n_in,
                              void* d_out, int out_size, void* d_ws, size_t ws_size,
                              hipStream_t stream) {
    const float* x = (const float*)d_in[0];   // [1024,1,32,32] f32
    const float* w = (const float*)d_in[1];   // [10,10,3] f32
    float* out   = (float*)d_out;             // [1024,1,32,32] f32
    float* gates = (float*)d_ws;              // 100*4 floats scratch

    gates_kernel<<<1, 128, 0, stream>>>(w, gates);
    sim_kernel<<<1024, 128, 0, stream>>>(x, gates, out);
}